// Round 1
// baseline (733.070 us; speedup 1.0000x reference)
//
#include <hip/hip_runtime.h>

#define NNODES 50000
#define NEDGES 800000

// ============================= CSR build =============================
__global__ void k_count(const int* __restrict__ dst, int* __restrict__ cnt, int ne) {
  int e = blockIdx.x * 256 + threadIdx.x;
  if (e < ne) atomicAdd(&cnt[dst[e]], 1);
}

__global__ __launch_bounds__(1024) void k_blocksum(const int* __restrict__ cnt,
                                                   int* __restrict__ bsum, int n) {
  __shared__ int sb[1024];
  int t = threadIdx.x, i = blockIdx.x * 1024 + t;
  sb[t] = (i < n) ? cnt[i] : 0;
  __syncthreads();
  for (int m = 512; m; m >>= 1) {
    if (t < m) sb[t] += sb[t + m];
    __syncthreads();
  }
  if (t == 0) bsum[blockIdx.x] = sb[0];
}

__global__ void k_scanb(const int* __restrict__ bsum, int* __restrict__ bpre, int nb) {
  if (threadIdx.x == 0) {
    int s = 0;
    for (int i = 0; i < nb; ++i) { bpre[i] = s; s += bsum[i]; }
  }
}

__global__ __launch_bounds__(1024) void k_scanwrite(int* __restrict__ cnt,
                                                    const int* __restrict__ bpre,
                                                    int* __restrict__ row_off, int n) {
  __shared__ int sb[1024];
  int t = threadIdx.x, i = blockIdx.x * 1024 + t;
  int v = (i < n) ? cnt[i] : 0;
  sb[t] = v;
  __syncthreads();
  for (int off = 1; off < 1024; off <<= 1) {
    int x = (t >= off) ? sb[t - off] : 0;
    __syncthreads();
    sb[t] += x;
    __syncthreads();
  }
  int incl = sb[t] + bpre[blockIdx.x];
  if (i < n) {
    row_off[i + 1] = incl;
    cnt[i] = incl - v;  // exclusive prefix -> scatter cursor
  }
  if (i == 0) row_off[0] = 0;
}

__global__ void k_fill(const int* __restrict__ src, const int* __restrict__ dst,
                       int* __restrict__ cursor, int* __restrict__ esrc, int ne) {
  int e = blockIdx.x * 256 + threadIdx.x;
  if (e < ne) {
    int pos = atomicAdd(&cursor[dst[e]], 1);
    esrc[pos] = src[e];
  }
}

// ============================= GEMM =============================
// C[r, c] = sum_k A[r,k] * B[k,c], A:[nrows,128], B:[128,NC].
// SPLIT: B is two [128,40] matrices side by side (NC=80), outputs split.
template <int NC, int JN, bool SPLIT>
__global__ __launch_bounds__(256) void k_gemm(const float* __restrict__ A,
                                              const float* __restrict__ B0,
                                              const float* __restrict__ B1,
                                              float* __restrict__ C0,
                                              float* __restrict__ C1, int nrows) {
  constexpr int LDB = NC + 4;  // pad keeps rows 16B-aligned (NC mult of 4) and shifts banks
  __shared__ float Wl[128 * LDB];
  __shared__ float Al[64 * 132];
  int t = threadIdx.x;
  int r0 = blockIdx.x * 64;

  // stage B (128 x NC) via float4
  constexpr int BQ = 128 * NC / 4;
  constexpr int BPT = BQ / 256;
  #pragma unroll
  for (int q0 = 0; q0 < BPT; ++q0) {
    int q = q0 * 256 + t;
    int k = q / (NC / 4), cq = q % (NC / 4);
    float4 v;
    if (!SPLIT) {
      v = *(const float4*)(B0 + k * NC + cq * 4);
    } else {
      int c = cq * 4;
      if (c < 40) v = *(const float4*)(B0 + k * 40 + c);
      else        v = *(const float4*)(B1 + k * 40 + (c - 40));
    }
    *(float4*)(&Wl[k * LDB + cq * 4]) = v;
  }
  // stage A (64 x 128) via float4
  #pragma unroll
  for (int q0 = 0; q0 < 8; ++q0) {
    int q = q0 * 256 + t;
    int r = q >> 5, kq = q & 31;
    float4 v = make_float4(0.f, 0.f, 0.f, 0.f);
    if (r0 + r < nrows) v = *(const float4*)(A + (size_t)(r0 + r) * 128 + kq * 4);
    *(float4*)(&Al[r * 132 + kq * 4]) = v;
  }
  __syncthreads();

  int tx = t & 15, ty = t >> 4;
  float acc[4][JN] = {};
  #pragma unroll 4
  for (int k = 0; k < 128; ++k) {
    float a[4];
    #pragma unroll
    for (int i = 0; i < 4; ++i) a[i] = Al[(ty * 4 + i) * 132 + k];
    #pragma unroll
    for (int j = 0; j < JN; ++j) {
      float b = Wl[k * LDB + tx + 16 * j];
      #pragma unroll
      for (int i = 0; i < 4; ++i) acc[i][j] += a[i] * b;
    }
  }

  #pragma unroll
  for (int i = 0; i < 4; ++i) {
    int r = r0 + ty * 4 + i;
    if (r >= nrows) continue;
    #pragma unroll
    for (int j = 0; j < JN; ++j) {
      int c = tx + 16 * j;
      if (!SPLIT) {
        C0[(size_t)r * NC + c] = acc[i][j];
      } else {
        if (c < 40) C0[(size_t)r * 40 + c] = acc[i][j];
        else        C1[(size_t)r * 40 + (c - 40)] = acc[i][j];
      }
    }
  }
}

// ============================= el / er =============================
// el[n,h] = sum_d feat[n,h*32+d]*al[h,d]  (H=4, D=32)
__global__ __launch_bounds__(256) void k_elr128(const float* __restrict__ feat,
                                                const float* __restrict__ al,
                                                const float* __restrict__ ar,
                                                float* __restrict__ el,
                                                float* __restrict__ er, int nnodes) {
  int t = threadIdx.x;
  int n = blockIdx.x * 2 + (t >> 7);
  if (n >= nnodes) return;
  int d = t & 127, h = d >> 5, dd = d & 31;
  float f = feat[(size_t)n * 128 + d];
  float pl = f * al[h * 32 + dd];
  float pr = f * ar[h * 32 + dd];
  #pragma unroll
  for (int m = 16; m; m >>= 1) {
    pl += __shfl_xor(pl, m);
    pr += __shfl_xor(pr, m);
  }
  if (dd == 0) {
    el[n * 4 + h] = pl;
    er[n * 4 + h] = pr;
  }
}

// H=1, D=40
__global__ __launch_bounds__(256) void k_elr40(const float* __restrict__ feat,
                                               const float* __restrict__ al,
                                               const float* __restrict__ ar,
                                               float* __restrict__ el,
                                               float* __restrict__ er, int nnodes) {
  int t = threadIdx.x;
  int n = blockIdx.x * 4 + (t >> 6);
  if (n >= nnodes) return;
  int lane = t & 63;
  float pl = 0.f, pr = 0.f;
  if (lane < 40) {
    float f = feat[(size_t)n * 40 + lane];
    pl = f * al[lane];
    pr = f * ar[lane];
  }
  #pragma unroll
  for (int m = 32; m; m >>= 1) {
    pl += __shfl_xor(pl, m);
    pr += __shfl_xor(pr, m);
  }
  if (lane == 0) {
    el[n] = pl;
    er[n] = pr;
  }
}

// ============================= message passing =============================
// One block (128 threads) per destination node. Softmax without max-shift
// (mathematically identical alpha; logits are tame). Fused residual + ELU.
template <bool RES, bool DOELU>
__global__ __launch_bounds__(128) void k_msg128(const float* __restrict__ feat,
                                                const float* __restrict__ el,
                                                const float* __restrict__ er,
                                                const int* __restrict__ row_off,
                                                const int* __restrict__ esrc,
                                                const float* __restrict__ hres,
                                                float* __restrict__ out) {
  int n = blockIdx.x;
  int d = threadIdx.x;
  int h = d >> 5;
  int s = row_off[n], e = row_off[n + 1];
  float ern = er[n * 4 + h];
  float den = 0.f;
  for (int j = s; j < e; ++j) {
    float x = el[esrc[j] * 4 + h] + ern;
    x = (x > 0.f) ? x : 0.2f * x;
    den += __expf(x);
  }
  float inv = (e > s) ? 1.f / den : 0.f;
  float acc = 0.f;
  for (int j = s; j < e; ++j) {
    int sj = esrc[j];
    float x = el[sj * 4 + h] + ern;
    x = (x > 0.f) ? x : 0.2f * x;
    acc += (__expf(x) * inv) * feat[(size_t)sj * 128 + d];
  }
  if (RES) acc += hres[(size_t)n * 128 + d];
  if (DOELU) acc = (acc > 0.f) ? acc : expm1f(acc);
  out[(size_t)n * 128 + d] = acc;
}

// Output layer: H=1, D=40, residual projection added, no activation.
__global__ __launch_bounds__(256) void k_msg40(const float* __restrict__ feat,
                                               const float* __restrict__ el,
                                               const float* __restrict__ er,
                                               const int* __restrict__ row_off,
                                               const int* __restrict__ esrc,
                                               const float* __restrict__ res,
                                               float* __restrict__ out, int nnodes) {
  int t = threadIdx.x;
  int n = blockIdx.x * 4 + (t >> 6);
  if (n >= nnodes) return;
  int lane = t & 63;
  int s = row_off[n], e = row_off[n + 1];
  float ern = er[n];
  float den = 0.f;
  for (int j = s; j < e; ++j) {
    float x = el[esrc[j]] + ern;
    x = (x > 0.f) ? x : 0.2f * x;
    den += __expf(x);
  }
  float inv = (e > s) ? 1.f / den : 0.f;
  if (lane < 40) {
    float acc = 0.f;
    for (int j = s; j < e; ++j) {
      int sj = esrc[j];
      float x = el[sj] + ern;
      x = (x > 0.f) ? x : 0.2f * x;
      acc += (__expf(x) * inv) * feat[(size_t)sj * 40 + lane];
    }
    out[(size_t)n * 40 + lane] = acc + res[(size_t)n * 40 + lane];
  }
}

// ============================= launch =============================
extern "C" void kernel_launch(void* const* d_in, const int* in_sizes, int n_in,
                              void* d_out, int out_size, void* d_ws, size_t ws_size,
                              hipStream_t stream) {
  const float* features = (const float*)d_in[0];
  const float* W0 = (const float*)d_in[1];
  const float* al0 = (const float*)d_in[2];
  const float* ar0 = (const float*)d_in[3];
  const float* W1 = (const float*)d_in[4];
  const float* al1 = (const float*)d_in[5];
  const float* ar1 = (const float*)d_in[6];
  const float* W2 = (const float*)d_in[7];
  const float* al2 = (const float*)d_in[8];
  const float* ar2 = (const float*)d_in[9];
  const float* resW2 = (const float*)d_in[10];
  const int* src = (const int*)d_in[11];
  const int* dst = (const int*)d_in[12];
  float* out = (float*)d_out;

  const int N = NNODES, E = NEDGES;
  char* w = (char*)d_ws;
  auto alloc = [&](size_t bytes) {
    char* p = w;
    w += (bytes + 255) & ~(size_t)255;
    return p;
  };
  int* cnt = (int*)alloc((size_t)N * 4);          // degree counts, then cursor
  int* row_off = (int*)alloc((size_t)(N + 1) * 4);
  int* bsum = (int*)alloc(256 * 4);
  int* bpre = (int*)alloc(256 * 4);
  int* esrc = (int*)alloc((size_t)E * 4);
  float* feat = (float*)alloc((size_t)N * 128 * 4);  // reused as feat2|res2 for layer 2
  float* el = (float*)alloc((size_t)N * 4 * 4);
  float* er = (float*)alloc((size_t)N * 4 * 4);
  float* h1 = (float*)alloc((size_t)N * 128 * 4);
  float* h2 = (float*)alloc((size_t)N * 128 * 4);
  float* feat2 = feat;
  float* res2 = feat + (size_t)N * 40;

  const int NB = (N + 1023) / 1024;  // 49

  // ---- CSR build ----
  hipMemsetAsync(cnt, 0, (size_t)N * 4, stream);
  k_count<<<(E + 255) / 256, 256, 0, stream>>>(dst, cnt, E);
  k_blocksum<<<NB, 1024, 0, stream>>>(cnt, bsum, N);
  k_scanb<<<1, 64, 0, stream>>>(bsum, bpre, NB);
  k_scanwrite<<<NB, 1024, 0, stream>>>(cnt, bpre, row_off, N);
  k_fill<<<(E + 255) / 256, 256, 0, stream>>>(src, dst, cnt, esrc, E);

  const int GB = (N + 63) / 64;  // 782

  // ---- layer 0 ----
  k_gemm<128, 8, false><<<GB, 256, 0, stream>>>(features, W0, nullptr, feat, nullptr, N);
  k_elr128<<<N / 2, 256, 0, stream>>>(feat, al0, ar0, el, er, N);
  k_msg128<false, true><<<N, 128, 0, stream>>>(feat, el, er, row_off, esrc, nullptr, h1);

  // ---- layer 1 ----
  k_gemm<128, 8, false><<<GB, 256, 0, stream>>>(h1, W1, nullptr, feat, nullptr, N);
  k_elr128<<<N / 2, 256, 0, stream>>>(feat, al1, ar1, el, er, N);
  k_msg128<true, true><<<N, 128, 0, stream>>>(feat, el, er, row_off, esrc, h1, h2);

  // ---- layer 2 (fused W2 | resW2 GEMM) ----
  k_gemm<80, 5, true><<<GB, 256, 0, stream>>>(h2, W2, resW2, feat2, res2, N);
  k_elr40<<<(N + 3) / 4, 256, 0, stream>>>(feat2, al2, ar2, el, er, N);
  k_msg40<<<(N + 3) / 4, 256, 0, stream>>>(feat2, el, er, row_off, esrc, res2, out, N);
}

// Round 2
// 421.577 us; speedup vs baseline: 1.7389x; 1.7389x over previous
//
#include <hip/hip_runtime.h>

#define NNODES 50000
#define NEDGES 800000

// ============================= CSR build =============================
__global__ void k_count(const int* __restrict__ dst, int* __restrict__ cnt, int ne) {
  int e = blockIdx.x * 256 + threadIdx.x;
  if (e < ne) atomicAdd(&cnt[dst[e]], 1);
}

__global__ __launch_bounds__(1024) void k_blocksum(const int* __restrict__ cnt,
                                                   int* __restrict__ bsum, int n) {
  __shared__ int sb[1024];
  int t = threadIdx.x, i = blockIdx.x * 1024 + t;
  sb[t] = (i < n) ? cnt[i] : 0;
  __syncthreads();
  for (int m = 512; m; m >>= 1) {
    if (t < m) sb[t] += sb[t + m];
    __syncthreads();
  }
  if (t == 0) bsum[blockIdx.x] = sb[0];
}

__global__ void k_scanb(const int* __restrict__ bsum, int* __restrict__ bpre, int nb) {
  if (threadIdx.x == 0) {
    int s = 0;
    for (int i = 0; i < nb; ++i) { bpre[i] = s; s += bsum[i]; }
  }
}

__global__ __launch_bounds__(1024) void k_scanwrite(int* __restrict__ cnt,
                                                    const int* __restrict__ bpre,
                                                    int* __restrict__ row_off, int n) {
  __shared__ int sb[1024];
  int t = threadIdx.x, i = blockIdx.x * 1024 + t;
  int v = (i < n) ? cnt[i] : 0;
  sb[t] = v;
  __syncthreads();
  for (int off = 1; off < 1024; off <<= 1) {
    int x = (t >= off) ? sb[t - off] : 0;
    __syncthreads();
    sb[t] += x;
    __syncthreads();
  }
  int incl = sb[t] + bpre[blockIdx.x];
  if (i < n) {
    row_off[i + 1] = incl;
    cnt[i] = incl - v;  // exclusive prefix -> scatter cursor
  }
  if (i == 0) row_off[0] = 0;
}

__global__ void k_fill(const int* __restrict__ src, const int* __restrict__ dst,
                       int* __restrict__ cursor, int* __restrict__ esrc, int ne) {
  int e = blockIdx.x * 256 + threadIdx.x;
  if (e < ne) {
    int pos = atomicAdd(&cursor[dst[e]], 1);
    esrc[pos] = src[e];
  }
}

// ============================= GEMM 128x128 =============================
// C[r,c] = sum_k A[r,k]*B[k,c]; A:[nrows,128], B:[128,128]. 512 thr, 128 rows/block.
__device__ __forceinline__ void fma4(float4& a, float s, const float4& b) {
  a.x += s * b.x; a.y += s * b.y; a.z += s * b.z; a.w += s * b.w;
}

__global__ __launch_bounds__(512) void k_gemm128(const float* __restrict__ A,
                                                 const float* __restrict__ B,
                                                 float* __restrict__ C, int nrows) {
  __shared__ float Bl[128 * 128];   // no pad: float4 reads have k fixed per instr
  __shared__ float Al[128 * 132];   // +4 pad breaks stride-512 bank alias on b32 reads
  int t = threadIdx.x;
  int r0 = blockIdx.x * 128;

  #pragma unroll
  for (int q0 = 0; q0 < 8; ++q0) {          // B: 128x32 quads
    int q = q0 * 512 + t;
    int k = q >> 5, cq = q & 31;
    *(float4*)(&Bl[k * 128 + cq * 4]) = *(const float4*)(B + k * 128 + cq * 4);
  }
  #pragma unroll
  for (int q0 = 0; q0 < 8; ++q0) {          // A: 128 rows x 32 quads
    int q = q0 * 512 + t;
    int r = q >> 5, kq = q & 31;
    float4 v = make_float4(0.f, 0.f, 0.f, 0.f);
    if (r0 + r < nrows) v = *(const float4*)(A + (size_t)(r0 + r) * 128 + kq * 4);
    *(float4*)(&Al[r * 132 + kq * 4]) = v;
  }
  __syncthreads();

  int tx = t & 15, ty = t >> 4;  // ty 0..31 -> rows ty*4+i ; cols tx*4(+64)
  float4 acc0[4] = {}, acc1[4] = {};
  #pragma unroll 4
  for (int k = 0; k < 128; ++k) {
    float a[4];
    #pragma unroll
    for (int i = 0; i < 4; ++i) a[i] = Al[(ty * 4 + i) * 132 + k];
    float4 b0 = *(const float4*)(&Bl[k * 128 + tx * 4]);
    float4 b1 = *(const float4*)(&Bl[k * 128 + tx * 4 + 64]);
    #pragma unroll
    for (int i = 0; i < 4; ++i) { fma4(acc0[i], a[i], b0); fma4(acc1[i], a[i], b1); }
  }
  #pragma unroll
  for (int i = 0; i < 4; ++i) {
    int r = r0 + ty * 4 + i;
    if (r >= nrows) continue;
    *(float4*)(C + (size_t)r * 128 + tx * 4) = acc0[i];
    *(float4*)(C + (size_t)r * 128 + tx * 4 + 64) = acc1[i];
  }
}

// ============================= GEMM split (layer 2) =============================
// B = [W2 | resW2] as 128x80; outputs split to C0 (stride 40) and C1 (stride 40).
__global__ __launch_bounds__(256) void k_gemm_split(const float* __restrict__ A,
                                                    const float* __restrict__ B0,
                                                    const float* __restrict__ B1,
                                                    float* __restrict__ C0,
                                                    float* __restrict__ C1, int nrows) {
  constexpr int NC = 80, JN = 5, LDB = 84;
  __shared__ float Wl[128 * LDB];
  __shared__ float Al[64 * 132];
  int t = threadIdx.x;
  int r0 = blockIdx.x * 64;

  #pragma unroll
  for (int q0 = 0; q0 < 128 * NC / 4 / 256; ++q0) {
    int q = q0 * 256 + t;
    int k = q / (NC / 4), cq = q % (NC / 4);
    int c = cq * 4;
    float4 v = (c < 40) ? *(const float4*)(B0 + k * 40 + c)
                        : *(const float4*)(B1 + k * 40 + (c - 40));
    *(float4*)(&Wl[k * LDB + c]) = v;
  }
  #pragma unroll
  for (int q0 = 0; q0 < 8; ++q0) {
    int q = q0 * 256 + t;
    int r = q >> 5, kq = q & 31;
    float4 v = make_float4(0.f, 0.f, 0.f, 0.f);
    if (r0 + r < nrows) v = *(const float4*)(A + (size_t)(r0 + r) * 128 + kq * 4);
    *(float4*)(&Al[r * 132 + kq * 4]) = v;
  }
  __syncthreads();

  int tx = t & 15, ty = t >> 4;
  float acc[4][JN] = {};
  #pragma unroll 4
  for (int k = 0; k < 128; ++k) {
    float a[4];
    #pragma unroll
    for (int i = 0; i < 4; ++i) a[i] = Al[(ty * 4 + i) * 132 + k];
    #pragma unroll
    for (int j = 0; j < JN; ++j) {
      float b = Wl[k * LDB + tx + 16 * j];
      #pragma unroll
      for (int i = 0; i < 4; ++i) acc[i][j] += a[i] * b;
    }
  }
  #pragma unroll
  for (int i = 0; i < 4; ++i) {
    int r = r0 + ty * 4 + i;
    if (r >= nrows) continue;
    #pragma unroll
    for (int j = 0; j < JN; ++j) {
      int c = tx + 16 * j;
      if (c < 40) C0[(size_t)r * 40 + c] = acc[i][j];
      else        C1[(size_t)r * 40 + (c - 40)] = acc[i][j];
    }
  }
}

// ============================= el / er =============================
__global__ __launch_bounds__(256) void k_elr128(const float* __restrict__ feat,
                                                const float* __restrict__ al,
                                                const float* __restrict__ ar,
                                                float* __restrict__ el,
                                                float* __restrict__ er, int nnodes) {
  int t = threadIdx.x;
  int n = blockIdx.x * 2 + (t >> 7);
  if (n >= nnodes) return;
  int d = t & 127, h = d >> 5, dd = d & 31;
  float f = feat[(size_t)n * 128 + d];
  float pl = f * al[h * 32 + dd];
  float pr = f * ar[h * 32 + dd];
  #pragma unroll
  for (int m = 16; m; m >>= 1) {
    pl += __shfl_xor(pl, m);
    pr += __shfl_xor(pr, m);
  }
  if (dd == 0) {
    el[n * 4 + h] = pl;
    er[n * 4 + h] = pr;
  }
}

__global__ __launch_bounds__(256) void k_elr40(const float* __restrict__ feat,
                                               const float* __restrict__ al,
                                               const float* __restrict__ ar,
                                               float* __restrict__ el,
                                               float* __restrict__ er, int nnodes) {
  int t = threadIdx.x;
  int n = blockIdx.x * 4 + (t >> 6);
  if (n >= nnodes) return;
  int lane = t & 63;
  float pl = 0.f, pr = 0.f;
  if (lane < 40) {
    float f = feat[(size_t)n * 40 + lane];
    pl = f * al[lane];
    pr = f * ar[lane];
  }
  #pragma unroll
  for (int m = 32; m; m >>= 1) {
    pl += __shfl_xor(pl, m);
    pr += __shfl_xor(pr, m);
  }
  if (lane == 0) {
    el[n] = pl;
    er[n] = pr;
  }
}

// ============================= message passing =============================
// Single pass: out = (sum_j w_j feat_j) / (sum_j w_j), normalization post-hoc.
// 32 lanes per node, float4 over the 128-dim; 8 nodes per 256-thread block.
template <bool RES, bool DOELU>
__global__ __launch_bounds__(256) void k_msg128v2(const float* __restrict__ feat,
                                                  const float* __restrict__ el,
                                                  const float* __restrict__ er,
                                                  const int* __restrict__ row_off,
                                                  const int* __restrict__ esrc,
                                                  const float* __restrict__ hres,
                                                  float* __restrict__ out, int nnodes) {
  int t = threadIdx.x;
  int n = blockIdx.x * 8 + (t >> 5);
  if (n >= nnodes) return;
  int lane = t & 31;          // float4 index over 128 cols
  int h = lane >> 3;          // head of this lane's 4 cols
  int s = row_off[n], e = row_off[n + 1];
  float ern = er[n * 4 + h];
  float4 acc = make_float4(0.f, 0.f, 0.f, 0.f);
  float den = 0.f;
  for (int j = s; j < e; ++j) {
    int sj = esrc[j];
    float x = el[sj * 4 + h] + ern;
    x = (x > 0.f) ? x : 0.2f * x;
    float w = __expf(x);
    den += w;
    float4 f = *(const float4*)(feat + (size_t)sj * 128 + lane * 4);
    fma4(acc, w, f);
  }
  float inv = (e > s) ? 1.f / den : 0.f;
  acc.x *= inv; acc.y *= inv; acc.z *= inv; acc.w *= inv;
  if (RES) {
    float4 r = *(const float4*)(hres + (size_t)n * 128 + lane * 4);
    acc.x += r.x; acc.y += r.y; acc.z += r.z; acc.w += r.w;
  }
  if (DOELU) {
    acc.x = (acc.x > 0.f) ? acc.x : expm1f(acc.x);
    acc.y = (acc.y > 0.f) ? acc.y : expm1f(acc.y);
    acc.z = (acc.z > 0.f) ? acc.z : expm1f(acc.z);
    acc.w = (acc.w > 0.f) ? acc.w : expm1f(acc.w);
  }
  *(float4*)(out + (size_t)n * 128 + lane * 4) = acc;
}

// Layer 2: H=1, D=40; 16 lanes per node (lanes 0..9 carry float4), 16 nodes/block.
__global__ __launch_bounds__(256) void k_msg40v2(const float* __restrict__ feat,
                                                 const float* __restrict__ el,
                                                 const float* __restrict__ er,
                                                 const int* __restrict__ row_off,
                                                 const int* __restrict__ esrc,
                                                 const float* __restrict__ res,
                                                 float* __restrict__ out, int nnodes) {
  int t = threadIdx.x;
  int n = blockIdx.x * 16 + (t >> 4);
  if (n >= nnodes) return;
  int lane = t & 15;
  int s = row_off[n], e = row_off[n + 1];
  float ern = er[n];
  float4 acc = make_float4(0.f, 0.f, 0.f, 0.f);
  float den = 0.f;
  for (int j = s; j < e; ++j) {
    int sj = esrc[j];
    float x = el[sj] + ern;
    x = (x > 0.f) ? x : 0.2f * x;
    float w = __expf(x);
    den += w;
    if (lane < 10) {
      float4 f = *(const float4*)(feat + (size_t)sj * 40 + lane * 4);
      fma4(acc, w, f);
    }
  }
  float inv = (e > s) ? 1.f / den : 0.f;
  if (lane < 10) {
    float4 r = *(const float4*)(res + (size_t)n * 40 + lane * 4);
    acc.x = acc.x * inv + r.x;
    acc.y = acc.y * inv + r.y;
    acc.z = acc.z * inv + r.z;
    acc.w = acc.w * inv + r.w;
    *(float4*)(out + (size_t)n * 40 + lane * 4) = acc;
  }
}

// ============================= launch =============================
extern "C" void kernel_launch(void* const* d_in, const int* in_sizes, int n_in,
                              void* d_out, int out_size, void* d_ws, size_t ws_size,
                              hipStream_t stream) {
  const float* features = (const float*)d_in[0];
  const float* W0 = (const float*)d_in[1];
  const float* al0 = (const float*)d_in[2];
  const float* ar0 = (const float*)d_in[3];
  const float* W1 = (const float*)d_in[4];
  const float* al1 = (const float*)d_in[5];
  const float* ar1 = (const float*)d_in[6];
  const float* W2 = (const float*)d_in[7];
  const float* al2 = (const float*)d_in[8];
  const float* ar2 = (const float*)d_in[9];
  const float* resW2 = (const float*)d_in[10];
  const int* src = (const int*)d_in[11];
  const int* dst = (const int*)d_in[12];
  float* out = (float*)d_out;

  const int N = NNODES, E = NEDGES;
  char* w = (char*)d_ws;
  auto alloc = [&](size_t bytes) {
    char* p = w;
    w += (bytes + 255) & ~(size_t)255;
    return p;
  };
  int* cnt = (int*)alloc((size_t)N * 4);
  int* row_off = (int*)alloc((size_t)(N + 1) * 4);
  int* bsum = (int*)alloc(256 * 4);
  int* bpre = (int*)alloc(256 * 4);
  int* esrc = (int*)alloc((size_t)E * 4);
  float* feat = (float*)alloc((size_t)N * 128 * 4);  // layer2: feat2|res2
  float* el = (float*)alloc((size_t)N * 4 * 4);
  float* er = (float*)alloc((size_t)N * 4 * 4);
  float* h1 = (float*)alloc((size_t)N * 128 * 4);
  float* h2 = (float*)alloc((size_t)N * 128 * 4);
  float* feat2 = feat;
  float* res2 = feat + (size_t)N * 40;

  const int NB = (N + 1023) / 1024;

  // ---- CSR build ----
  hipMemsetAsync(cnt, 0, (size_t)N * 4, stream);
  k_count<<<(E + 255) / 256, 256, 0, stream>>>(dst, cnt, E);
  k_blocksum<<<NB, 1024, 0, stream>>>(cnt, bsum, N);
  k_scanb<<<1, 64, 0, stream>>>(bsum, bpre, NB);
  k_scanwrite<<<NB, 1024, 0, stream>>>(cnt, bpre, row_off, N);
  k_fill<<<(E + 255) / 256, 256, 0, stream>>>(src, dst, cnt, esrc, E);

  const int GB128 = (N + 127) / 128;  // 391
  const int GB64 = (N + 63) / 64;     // 782

  // ---- layer 0 ----
  k_gemm128<<<GB128, 512, 0, stream>>>(features, W0, feat, N);
  k_elr128<<<N / 2, 256, 0, stream>>>(feat, al0, ar0, el, er, N);
  k_msg128v2<false, true><<<(N + 7) / 8, 256, 0, stream>>>(feat, el, er, row_off, esrc, nullptr, h1, N);

  // ---- layer 1 ----
  k_gemm128<<<GB128, 512, 0, stream>>>(h1, W1, feat, N);
  k_elr128<<<N / 2, 256, 0, stream>>>(feat, al1, ar1, el, er, N);
  k_msg128v2<true, true><<<(N + 7) / 8, 256, 0, stream>>>(feat, el, er, row_off, esrc, h1, h2, N);

  // ---- layer 2 ----
  k_gemm_split<<<GB64, 256, 0, stream>>>(h2, W2, resW2, feat2, res2, N);
  k_elr40<<<(N + 3) / 4, 256, 0, stream>>>(feat2, al2, ar2, el, er, N);
  k_msg40v2<<<(N + 15) / 16, 256, 0, stream>>>(feat2, el, er, row_off, esrc, res2, out, N);
}

// Round 3
// 368.743 us; speedup vs baseline: 1.9880x; 1.1433x over previous
//
#include <hip/hip_runtime.h>

#define NNODES 50000
#define NEDGES 800000

// ============================= CSR build =============================
__global__ void k_count(const int* __restrict__ dst, int* __restrict__ cnt, int ne) {
  int e = blockIdx.x * 256 + threadIdx.x;
  if (e < ne) atomicAdd(&cnt[dst[e]], 1);
}

__global__ __launch_bounds__(1024) void k_blocksum(const int* __restrict__ cnt,
                                                   int* __restrict__ bsum, int n) {
  __shared__ int sb[1024];
  int t = threadIdx.x, i = blockIdx.x * 1024 + t;
  sb[t] = (i < n) ? cnt[i] : 0;
  __syncthreads();
  for (int m = 512; m; m >>= 1) {
    if (t < m) sb[t] += sb[t + m];
    __syncthreads();
  }
  if (t == 0) bsum[blockIdx.x] = sb[0];
}

__global__ void k_scanb(const int* __restrict__ bsum, int* __restrict__ bpre, int nb) {
  if (threadIdx.x == 0) {
    int s = 0;
    for (int i = 0; i < nb; ++i) { bpre[i] = s; s += bsum[i]; }
  }
}

__global__ __launch_bounds__(1024) void k_scanwrite(int* __restrict__ cnt,
                                                    const int* __restrict__ bpre,
                                                    int* __restrict__ row_off, int n) {
  __shared__ int sb[1024];
  int t = threadIdx.x, i = blockIdx.x * 1024 + t;
  int v = (i < n) ? cnt[i] : 0;
  sb[t] = v;
  __syncthreads();
  for (int off = 1; off < 1024; off <<= 1) {
    int x = (t >= off) ? sb[t - off] : 0;
    __syncthreads();
    sb[t] += x;
    __syncthreads();
  }
  int incl = sb[t] + bpre[blockIdx.x];
  if (i < n) {
    row_off[i + 1] = incl;
    cnt[i] = incl - v;  // exclusive prefix -> scatter cursor
  }
  if (i == 0) row_off[0] = 0;
}

__global__ void k_fill(const int* __restrict__ src, const int* __restrict__ dst,
                       int* __restrict__ cursor, int* __restrict__ esrc, int ne) {
  int e = blockIdx.x * 256 + threadIdx.x;
  if (e < ne) {
    int pos = atomicAdd(&cursor[dst[e]], 1);
    esrc[pos] = src[e];
  }
}

// ============================= GEMM 128x128 + fused el/er =============================
__device__ __forceinline__ void fma4(float4& a, float s, const float4& b) {
  a.x += s * b.x; a.y += s * b.y; a.z += s * b.z; a.w += s * b.w;
}
__device__ __forceinline__ float dot4(const float4& a, const float* b) {
  return a.x * b[0] + a.y * b[1] + a.z * b[2] + a.w * b[3];
}

// C = A@B (A:[nrows,128], B:[128,128]); epilogue computes el[r,h]=sum_d C*al, er likewise.
__global__ __launch_bounds__(512) void k_gemm128(const float* __restrict__ A,
                                                 const float* __restrict__ B,
                                                 const float* __restrict__ al,
                                                 const float* __restrict__ ar,
                                                 float* __restrict__ C,
                                                 float* __restrict__ el,
                                                 float* __restrict__ er, int nrows) {
  __shared__ float Bl[128 * 128];
  __shared__ float Al[128 * 132];
  int t = threadIdx.x;
  int r0 = blockIdx.x * 128;

  #pragma unroll
  for (int q0 = 0; q0 < 8; ++q0) {
    int q = q0 * 512 + t;
    int k = q >> 5, cq = q & 31;
    *(float4*)(&Bl[k * 128 + cq * 4]) = *(const float4*)(B + k * 128 + cq * 4);
  }
  #pragma unroll
  for (int q0 = 0; q0 < 8; ++q0) {
    int q = q0 * 512 + t;
    int r = q >> 5, kq = q & 31;
    float4 v = make_float4(0.f, 0.f, 0.f, 0.f);
    if (r0 + r < nrows) v = *(const float4*)(A + (size_t)(r0 + r) * 128 + kq * 4);
    *(float4*)(&Al[r * 132 + kq * 4]) = v;
  }
  __syncthreads();

  int tx = t & 15, ty = t >> 4;  // rows ty*4+i, cols tx*4 and tx*4+64
  float4 acc0[4] = {}, acc1[4] = {};
  #pragma unroll 4
  for (int k = 0; k < 128; ++k) {
    float a[4];
    #pragma unroll
    for (int i = 0; i < 4; ++i) a[i] = Al[(ty * 4 + i) * 132 + k];
    float4 b0 = *(const float4*)(&Bl[k * 128 + tx * 4]);
    float4 b1 = *(const float4*)(&Bl[k * 128 + tx * 4 + 64]);
    #pragma unroll
    for (int i = 0; i < 4; ++i) { fma4(acc0[i], a[i], b0); fma4(acc1[i], a[i], b1); }
  }

  // attention-vector slices for this thread's columns
  float ala[4], alb[4], ara[4], arb[4];
  #pragma unroll
  for (int c = 0; c < 4; ++c) {
    ala[c] = al[tx * 4 + c];  alb[c] = al[64 + tx * 4 + c];
    ara[c] = ar[tx * 4 + c];  arb[c] = ar[64 + tx * 4 + c];
  }
  int ha = tx >> 3;  // head of a-block cols (0 or 1); b-block head = ha+2

  #pragma unroll
  for (int i = 0; i < 4; ++i) {
    int r = r0 + ty * 4 + i;
    bool ok = (r < nrows);
    if (ok) {
      *(float4*)(C + (size_t)r * 128 + tx * 4) = acc0[i];
      *(float4*)(C + (size_t)r * 128 + tx * 4 + 64) = acc1[i];
    }
    float pla = dot4(acc0[i], ala), plb = dot4(acc1[i], alb);
    float pra = dot4(acc0[i], ara), prb = dot4(acc1[i], arb);
    #pragma unroll
    for (int m = 1; m < 8; m <<= 1) {
      pla += __shfl_xor(pla, m); plb += __shfl_xor(plb, m);
      pra += __shfl_xor(pra, m); prb += __shfl_xor(prb, m);
    }
    if (ok && (tx & 7) == 0) {
      el[r * 4 + ha] = pla;  el[r * 4 + 2 + ha] = plb;
      er[r * 4 + ha] = pra;  er[r * 4 + 2 + ha] = prb;
    }
  }
}

// ============================= GEMM split (layer 2) =============================
__global__ __launch_bounds__(256) void k_gemm_split(const float* __restrict__ A,
                                                    const float* __restrict__ B0,
                                                    const float* __restrict__ B1,
                                                    float* __restrict__ C0,
                                                    float* __restrict__ C1, int nrows) {
  constexpr int NC = 80, JN = 5, LDB = 84;
  __shared__ float Wl[128 * LDB];
  __shared__ float Al[64 * 132];
  int t = threadIdx.x;
  int r0 = blockIdx.x * 64;

  #pragma unroll
  for (int q0 = 0; q0 < 128 * NC / 4 / 256; ++q0) {
    int q = q0 * 256 + t;
    int k = q / (NC / 4), cq = q % (NC / 4);
    int c = cq * 4;
    float4 v = (c < 40) ? *(const float4*)(B0 + k * 40 + c)
                        : *(const float4*)(B1 + k * 40 + (c - 40));
    *(float4*)(&Wl[k * LDB + c]) = v;
  }
  #pragma unroll
  for (int q0 = 0; q0 < 8; ++q0) {
    int q = q0 * 256 + t;
    int r = q >> 5, kq = q & 31;
    float4 v = make_float4(0.f, 0.f, 0.f, 0.f);
    if (r0 + r < nrows) v = *(const float4*)(A + (size_t)(r0 + r) * 128 + kq * 4);
    *(float4*)(&Al[r * 132 + kq * 4]) = v;
  }
  __syncthreads();

  int tx = t & 15, ty = t >> 4;
  float acc[4][JN] = {};
  #pragma unroll 4
  for (int k = 0; k < 128; ++k) {
    float a[4];
    #pragma unroll
    for (int i = 0; i < 4; ++i) a[i] = Al[(ty * 4 + i) * 132 + k];
    #pragma unroll
    for (int j = 0; j < JN; ++j) {
      float b = Wl[k * LDB + tx + 16 * j];
      #pragma unroll
      for (int i = 0; i < 4; ++i) acc[i][j] += a[i] * b;
    }
  }
  #pragma unroll
  for (int i = 0; i < 4; ++i) {
    int r = r0 + ty * 4 + i;
    if (r >= nrows) continue;
    #pragma unroll
    for (int j = 0; j < JN; ++j) {
      int c = tx + 16 * j;
      if (c < 40) C0[(size_t)r * 40 + c] = acc[i][j];
      else        C1[(size_t)r * 40 + (c - 40)] = acc[i][j];
    }
  }
}

// ============================= el / er (layer 2 only) =============================
__global__ __launch_bounds__(256) void k_elr40(const float* __restrict__ feat,
                                               const float* __restrict__ al,
                                               const float* __restrict__ ar,
                                               float* __restrict__ el,
                                               float* __restrict__ er, int nnodes) {
  int t = threadIdx.x;
  int n = blockIdx.x * 4 + (t >> 6);
  if (n >= nnodes) return;
  int lane = t & 63;
  float pl = 0.f, pr = 0.f;
  if (lane < 40) {
    float f = feat[(size_t)n * 40 + lane];
    pl = f * al[lane];
    pr = f * ar[lane];
  }
  #pragma unroll
  for (int m = 32; m; m >>= 1) {
    pl += __shfl_xor(pl, m);
    pr += __shfl_xor(pr, m);
  }
  if (lane == 0) {
    el[n] = pl;
    er[n] = pr;
  }
}

// ============================= message passing v3 =============================
// Chunked register-broadcast: per 32-edge chunk, one coalesced esrc load + 4
// prefetched el gathers per lane; edge loop has no dependent loads except the
// feat gather (address via shfl). 4 independent accumulator chains.
template <bool RES, bool DOELU>
__global__ __launch_bounds__(256) void k_msg128v3(const float* __restrict__ feat,
                                                  const float* __restrict__ el,
                                                  const float* __restrict__ er,
                                                  const int* __restrict__ row_off,
                                                  const int* __restrict__ esrc,
                                                  const float* __restrict__ hres,
                                                  float* __restrict__ out, int nnodes) {
  int t = threadIdx.x;
  int n = blockIdx.x * 8 + (t >> 5);
  if (n >= nnodes) return;
  int lane = t & 31;          // float4 index over 128 cols
  int h = lane >> 3;          // this lane's head
  int s = row_off[n], e = row_off[n + 1];
  float ern = er[n * 4 + h];
  float4 acc[4] = {};
  float den[4] = {0.f, 0.f, 0.f, 0.f};

  for (int c = s; c < e; c += 32) {
    int m = e - c; if (m > 32) m = 32;
    int sjv = 0;
    if (lane < m) sjv = esrc[c + lane];
    // prefetch el for sub-chunks of 8: lane covers edge (lane&7)+8k, own head
    int e0 = __shfl(sjv, (lane & 7), 32);
    int e1 = __shfl(sjv, (lane & 7) + 8, 32);
    int e2 = __shfl(sjv, (lane & 7) + 16, 32);
    int e3 = __shfl(sjv, (lane & 7) + 24, 32);
    float sel0 = el[e0 * 4 + h];
    float sel1 = el[e1 * 4 + h];
    float sel2 = el[e2 * 4 + h];
    float sel3 = el[e3 * 4 + h];

#define GAT_SUB(KK, SEL)                                                      \
    {                                                                         \
      int b = KK * 8;                                                         \
      if (b < m) {                                                            \
        int mm = m - b; if (mm > 8) mm = 8;                                   \
        _Pragma("unroll")                                                     \
        for (int j = 0; j < 8; ++j) {                                         \
          if (j < mm) {                                                       \
            float ev = __shfl(SEL, (lane & 24) + j, 32);                      \
            float x = ev + ern;                                               \
            x = fmaxf(x, 0.2f * x);                                           \
            float wgt = __expf(x);                                            \
            int sj = __shfl(sjv, b + j, 32);                                  \
            den[j & 3] += wgt;                                                \
            float4 f = *(const float4*)(feat + (size_t)sj * 128 + lane * 4);  \
            fma4(acc[j & 3], wgt, f);                                         \
          }                                                                   \
        }                                                                     \
      }                                                                       \
    }
    GAT_SUB(0, sel0)
    GAT_SUB(1, sel1)
    GAT_SUB(2, sel2)
    GAT_SUB(3, sel3)
#undef GAT_SUB
  }

  float4 A;
  A.x = acc[0].x + acc[1].x + acc[2].x + acc[3].x;
  A.y = acc[0].y + acc[1].y + acc[2].y + acc[3].y;
  A.z = acc[0].z + acc[1].z + acc[2].z + acc[3].z;
  A.w = acc[0].w + acc[1].w + acc[2].w + acc[3].w;
  float D = (den[0] + den[1]) + (den[2] + den[3]);
  float inv = (e > s) ? 1.f / D : 0.f;
  A.x *= inv; A.y *= inv; A.z *= inv; A.w *= inv;
  if (RES) {
    float4 r = *(const float4*)(hres + (size_t)n * 128 + lane * 4);
    A.x += r.x; A.y += r.y; A.z += r.z; A.w += r.w;
  }
  if (DOELU) {
    A.x = (A.x > 0.f) ? A.x : expm1f(A.x);
    A.y = (A.y > 0.f) ? A.y : expm1f(A.y);
    A.z = (A.z > 0.f) ? A.z : expm1f(A.z);
    A.w = (A.w > 0.f) ? A.w : expm1f(A.w);
  }
  *(float4*)(out + (size_t)n * 128 + lane * 4) = A;
}

// Layer 2: H=1, D=40; 16 lanes/node, chunked 16 edges, lanes 0..9 carry float4.
__global__ __launch_bounds__(256) void k_msg40v3(const float* __restrict__ feat,
                                                 const float* __restrict__ el,
                                                 const float* __restrict__ er,
                                                 const int* __restrict__ row_off,
                                                 const int* __restrict__ esrc,
                                                 const float* __restrict__ res,
                                                 float* __restrict__ out, int nnodes) {
  int t = threadIdx.x;
  int n = blockIdx.x * 16 + (t >> 4);
  if (n >= nnodes) return;
  int lane = t & 15;
  int s = row_off[n], e = row_off[n + 1];
  float ern = er[n];
  float4 acc[2] = {};
  float den[2] = {0.f, 0.f};

  for (int c = s; c < e; c += 16) {
    int m = e - c; if (m > 16) m = 16;
    int sjv = 0;
    if (lane < m) sjv = esrc[c + lane];
    float selv = el[sjv];
    #pragma unroll
    for (int j = 0; j < 16; ++j) {
      if (j < m) {
        float ev = __shfl(selv, j, 16);
        float x = ev + ern;
        x = fmaxf(x, 0.2f * x);
        float wgt = __expf(x);
        int sj = __shfl(sjv, j, 16);
        den[j & 1] += wgt;
        if (lane < 10) {
          float4 f = *(const float4*)(feat + (size_t)sj * 40 + lane * 4);
          fma4(acc[j & 1], wgt, f);
        }
      }
    }
  }
  float D = den[0] + den[1];
  float inv = (e > s) ? 1.f / D : 0.f;
  if (lane < 10) {
    float4 r = *(const float4*)(res + (size_t)n * 40 + lane * 4);
    float4 A;
    A.x = (acc[0].x + acc[1].x) * inv + r.x;
    A.y = (acc[0].y + acc[1].y) * inv + r.y;
    A.z = (acc[0].z + acc[1].z) * inv + r.z;
    A.w = (acc[0].w + acc[1].w) * inv + r.w;
    *(float4*)(out + (size_t)n * 40 + lane * 4) = A;
  }
}

// ============================= launch =============================
extern "C" void kernel_launch(void* const* d_in, const int* in_sizes, int n_in,
                              void* d_out, int out_size, void* d_ws, size_t ws_size,
                              hipStream_t stream) {
  const float* features = (const float*)d_in[0];
  const float* W0 = (const float*)d_in[1];
  const float* al0 = (const float*)d_in[2];
  const float* ar0 = (const float*)d_in[3];
  const float* W1 = (const float*)d_in[4];
  const float* al1 = (const float*)d_in[5];
  const float* ar1 = (const float*)d_in[6];
  const float* W2 = (const float*)d_in[7];
  const float* al2 = (const float*)d_in[8];
  const float* ar2 = (const float*)d_in[9];
  const float* resW2 = (const float*)d_in[10];
  const int* src = (const int*)d_in[11];
  const int* dst = (const int*)d_in[12];
  float* out = (float*)d_out;

  const int N = NNODES, E = NEDGES;
  char* w = (char*)d_ws;
  auto alloc = [&](size_t bytes) {
    char* p = w;
    w += (bytes + 255) & ~(size_t)255;
    return p;
  };
  int* cnt = (int*)alloc((size_t)N * 4);
  int* row_off = (int*)alloc((size_t)(N + 1) * 4);
  int* bsum = (int*)alloc(256 * 4);
  int* bpre = (int*)alloc(256 * 4);
  int* esrc = (int*)alloc((size_t)E * 4);
  float* feat = (float*)alloc((size_t)N * 128 * 4);  // layer2: feat2|res2
  float* el = (float*)alloc((size_t)N * 4 * 4);
  float* er = (float*)alloc((size_t)N * 4 * 4);
  float* h1 = (float*)alloc((size_t)N * 128 * 4);
  float* h2 = (float*)alloc((size_t)N * 128 * 4);
  float* feat2 = feat;
  float* res2 = feat + (size_t)N * 40;

  const int NB = (N + 1023) / 1024;

  // ---- CSR build ----
  hipMemsetAsync(cnt, 0, (size_t)N * 4, stream);
  k_count<<<(E + 255) / 256, 256, 0, stream>>>(dst, cnt, E);
  k_blocksum<<<NB, 1024, 0, stream>>>(cnt, bsum, N);
  k_scanb<<<1, 64, 0, stream>>>(bsum, bpre, NB);
  k_scanwrite<<<NB, 1024, 0, stream>>>(cnt, bpre, row_off, N);
  k_fill<<<(E + 255) / 256, 256, 0, stream>>>(src, dst, cnt, esrc, E);

  const int GB128 = (N + 127) / 128;  // 391
  const int GB64 = (N + 63) / 64;     // 782

  // ---- layer 0 ----
  k_gemm128<<<GB128, 512, 0, stream>>>(features, W0, al0, ar0, feat, el, er, N);
  k_msg128v3<false, true><<<(N + 7) / 8, 256, 0, stream>>>(feat, el, er, row_off, esrc, nullptr, h1, N);

  // ---- layer 1 ----
  k_gemm128<<<GB128, 512, 0, stream>>>(h1, W1, al1, ar1, feat, el, er, N);
  k_msg128v3<true, true><<<(N + 7) / 8, 256, 0, stream>>>(feat, el, er, row_off, esrc, h1, h2, N);

  // ---- layer 2 ----
  k_gemm_split<<<GB64, 256, 0, stream>>>(h2, W2, resW2, feat2, res2, N);
  k_elr40<<<(N + 3) / 4, 256, 0, stream>>>(feat2, al2, ar2, el, er, N);
  k_msg40v3<<<(N + 15) / 16, 256, 0, stream>>>(feat2, el, er, row_off, esrc, res2, out, N);
}

// Round 4
// 326.193 us; speedup vs baseline: 2.2473x; 1.1304x over previous
//
#include <hip/hip_runtime.h>
#include <hip/hip_fp16.h>

#define NNODES 50000
#define NEDGES 800000

// ============================= CSR build =============================
__global__ void k_count(const int* __restrict__ dst, int* __restrict__ cnt, int ne) {
  int e = blockIdx.x * 256 + threadIdx.x;
  if (e < ne) atomicAdd(&cnt[dst[e]], 1);
}

__global__ __launch_bounds__(1024) void k_blocksum(const int* __restrict__ cnt,
                                                   int* __restrict__ bsum, int n) {
  __shared__ int sb[1024];
  int t = threadIdx.x, i = blockIdx.x * 1024 + t;
  sb[t] = (i < n) ? cnt[i] : 0;
  __syncthreads();
  for (int m = 512; m; m >>= 1) {
    if (t < m) sb[t] += sb[t + m];
    __syncthreads();
  }
  if (t == 0) bsum[blockIdx.x] = sb[0];
}

__global__ void k_scanb(const int* __restrict__ bsum, int* __restrict__ bpre, int nb) {
  if (threadIdx.x == 0) {
    int s = 0;
    for (int i = 0; i < nb; ++i) { bpre[i] = s; s += bsum[i]; }
  }
}

__global__ __launch_bounds__(1024) void k_scanwrite(int* __restrict__ cnt,
                                                    const int* __restrict__ bpre,
                                                    int* __restrict__ row_off, int n) {
  __shared__ int sb[1024];
  int t = threadIdx.x, i = blockIdx.x * 1024 + t;
  int v = (i < n) ? cnt[i] : 0;
  sb[t] = v;
  __syncthreads();
  for (int off = 1; off < 1024; off <<= 1) {
    int x = (t >= off) ? sb[t - off] : 0;
    __syncthreads();
    sb[t] += x;
    __syncthreads();
  }
  int incl = sb[t] + bpre[blockIdx.x];
  if (i < n) {
    row_off[i + 1] = incl;
    cnt[i] = incl - v;  // exclusive prefix -> scatter cursor
  }
  if (i == 0) row_off[0] = 0;
}

__global__ void k_fill(const int* __restrict__ src, const int* __restrict__ dst,
                       int* __restrict__ cursor, int* __restrict__ esrc, int ne) {
  int e = blockIdx.x * 256 + threadIdx.x;
  if (e < ne) {
    int pos = atomicAdd(&cursor[dst[e]], 1);
    esrc[pos] = src[e];
  }
}

// ============================= helpers =============================
__device__ __forceinline__ void fma4(float4& a, float s, const float4& b) {
  a.x += s * b.x; a.y += s * b.y; a.z += s * b.z; a.w += s * b.w;
}
__device__ __forceinline__ float dot4(const float4& a, const float* b) {
  return a.x * b[0] + a.y * b[1] + a.z * b[2] + a.w * b[3];
}
__device__ __forceinline__ void fma8h(float4& a0, float4& a1, float w, const uint4& r) {
  const __half2* hp = (const __half2*)&r;
  float2 f0 = __half22float2(hp[0]);
  float2 f1 = __half22float2(hp[1]);
  float2 f2 = __half22float2(hp[2]);
  float2 f3 = __half22float2(hp[3]);
  a0.x += w * f0.x; a0.y += w * f0.y; a0.z += w * f1.x; a0.w += w * f1.y;
  a1.x += w * f2.x; a1.y += w * f2.y; a1.z += w * f3.x; a1.w += w * f3.y;
}

// ============================= GEMM 128x128 + fused el/er, fp16 C ===========
__global__ __launch_bounds__(512) void k_gemm128(const float* __restrict__ A,
                                                 const float* __restrict__ B,
                                                 const float* __restrict__ al,
                                                 const float* __restrict__ ar,
                                                 __half* __restrict__ C,
                                                 float* __restrict__ el,
                                                 float* __restrict__ er, int nrows) {
  __shared__ float Bl[128 * 128];
  __shared__ float Al[128 * 132];
  int t = threadIdx.x;
  int r0 = blockIdx.x * 128;

  #pragma unroll
  for (int q0 = 0; q0 < 8; ++q0) {
    int q = q0 * 512 + t;
    int k = q >> 5, cq = q & 31;
    *(float4*)(&Bl[k * 128 + cq * 4]) = *(const float4*)(B + k * 128 + cq * 4);
  }
  #pragma unroll
  for (int q0 = 0; q0 < 8; ++q0) {
    int q = q0 * 512 + t;
    int r = q >> 5, kq = q & 31;
    float4 v = make_float4(0.f, 0.f, 0.f, 0.f);
    if (r0 + r < nrows) v = *(const float4*)(A + (size_t)(r0 + r) * 128 + kq * 4);
    *(float4*)(&Al[r * 132 + kq * 4]) = v;
  }
  __syncthreads();

  int tx = t & 15, ty = t >> 4;  // rows ty*4+i, cols tx*4 and tx*4+64
  float4 acc0[4] = {}, acc1[4] = {};
  #pragma unroll 4
  for (int k = 0; k < 128; ++k) {
    float a[4];
    #pragma unroll
    for (int i = 0; i < 4; ++i) a[i] = Al[(ty * 4 + i) * 132 + k];
    float4 b0 = *(const float4*)(&Bl[k * 128 + tx * 4]);
    float4 b1 = *(const float4*)(&Bl[k * 128 + tx * 4 + 64]);
    #pragma unroll
    for (int i = 0; i < 4; ++i) { fma4(acc0[i], a[i], b0); fma4(acc1[i], a[i], b1); }
  }

  float ala[4], alb[4], ara[4], arb[4];
  #pragma unroll
  for (int c = 0; c < 4; ++c) {
    ala[c] = al[tx * 4 + c];  alb[c] = al[64 + tx * 4 + c];
    ara[c] = ar[tx * 4 + c];  arb[c] = ar[64 + tx * 4 + c];
  }
  int ha = tx >> 3;  // head of a-block cols (0/1); b-block head = ha+2

  #pragma unroll
  for (int i = 0; i < 4; ++i) {
    int r = r0 + ty * 4 + i;
    bool ok = (r < nrows);
    if (ok) {
      __half2 p0[2] = {__floats2half2_rn(acc0[i].x, acc0[i].y),
                       __floats2half2_rn(acc0[i].z, acc0[i].w)};
      __half2 p1[2] = {__floats2half2_rn(acc1[i].x, acc1[i].y),
                       __floats2half2_rn(acc1[i].z, acc1[i].w)};
      *(uint2*)(C + (size_t)r * 128 + tx * 4) = *(uint2*)p0;
      *(uint2*)(C + (size_t)r * 128 + tx * 4 + 64) = *(uint2*)p1;
    }
    float pla = dot4(acc0[i], ala), plb = dot4(acc1[i], alb);
    float pra = dot4(acc0[i], ara), prb = dot4(acc1[i], arb);
    #pragma unroll
    for (int m = 1; m < 8; m <<= 1) {
      pla += __shfl_xor(pla, m); plb += __shfl_xor(plb, m);
      pra += __shfl_xor(pra, m); prb += __shfl_xor(prb, m);
    }
    if (ok && (tx & 7) == 0) {
      el[r * 4 + ha] = pla;  el[r * 4 + 2 + ha] = plb;
      er[r * 4 + ha] = pra;  er[r * 4 + 2 + ha] = prb;
    }
  }
}

// ============================= GEMM split (layer 2) =========================
// C0 (gathered) -> fp16; C1 (residual, read per-node) stays f32.
__global__ __launch_bounds__(256) void k_gemm_split(const float* __restrict__ A,
                                                    const float* __restrict__ B0,
                                                    const float* __restrict__ B1,
                                                    __half* __restrict__ C0,
                                                    float* __restrict__ C1, int nrows) {
  constexpr int NC = 80, JN = 5, LDB = 84;
  __shared__ float Wl[128 * LDB];
  __shared__ float Al[64 * 132];
  int t = threadIdx.x;
  int r0 = blockIdx.x * 64;

  #pragma unroll
  for (int q0 = 0; q0 < 128 * NC / 4 / 256; ++q0) {
    int q = q0 * 256 + t;
    int k = q / (NC / 4), cq = q % (NC / 4);
    int c = cq * 4;
    float4 v = (c < 40) ? *(const float4*)(B0 + k * 40 + c)
                        : *(const float4*)(B1 + k * 40 + (c - 40));
    *(float4*)(&Wl[k * LDB + c]) = v;
  }
  #pragma unroll
  for (int q0 = 0; q0 < 8; ++q0) {
    int q = q0 * 256 + t;
    int r = q >> 5, kq = q & 31;
    float4 v = make_float4(0.f, 0.f, 0.f, 0.f);
    if (r0 + r < nrows) v = *(const float4*)(A + (size_t)(r0 + r) * 128 + kq * 4);
    *(float4*)(&Al[r * 132 + kq * 4]) = v;
  }
  __syncthreads();

  int tx = t & 15, ty = t >> 4;
  float acc[4][JN] = {};
  #pragma unroll 4
  for (int k = 0; k < 128; ++k) {
    float a[4];
    #pragma unroll
    for (int i = 0; i < 4; ++i) a[i] = Al[(ty * 4 + i) * 132 + k];
    #pragma unroll
    for (int j = 0; j < JN; ++j) {
      float b = Wl[k * LDB + tx + 16 * j];
      #pragma unroll
      for (int i = 0; i < 4; ++i) acc[i][j] += a[i] * b;
    }
  }
  #pragma unroll
  for (int i = 0; i < 4; ++i) {
    int r = r0 + ty * 4 + i;
    if (r >= nrows) continue;
    #pragma unroll
    for (int j = 0; j < JN; ++j) {
      int c = tx + 16 * j;
      if (c < 40) C0[(size_t)r * 40 + c] = __float2half_rn(acc[i][j]);
      else        C1[(size_t)r * 40 + (c - 40)] = acc[i][j];
    }
  }
}

// ============================= el / er (layer 2 only) =======================
__global__ __launch_bounds__(256) void k_elr40(const __half* __restrict__ feat,
                                               const float* __restrict__ al,
                                               const float* __restrict__ ar,
                                               float* __restrict__ el,
                                               float* __restrict__ er, int nnodes) {
  int t = threadIdx.x;
  int n = blockIdx.x * 4 + (t >> 6);
  if (n >= nnodes) return;
  int lane = t & 63;
  float pl = 0.f, pr = 0.f;
  if (lane < 40) {
    float f = __half2float(feat[(size_t)n * 40 + lane]);
    pl = f * al[lane];
    pr = f * ar[lane];
  }
  #pragma unroll
  for (int m = 32; m; m >>= 1) {
    pl += __shfl_xor(pl, m);
    pr += __shfl_xor(pr, m);
  }
  if (lane == 0) {
    el[n] = pl;
    er[n] = pr;
  }
}

// ============================= message passing v4 (fp16 gather) =============
// 16 lanes/node, each lane owns 8 cols (one uint4 = 8 halves per edge).
// Per 16-edge chunk: coalesced esrc load, 4 el prefetch gathers/lane,
// edge loop with shfl-broadcast addresses and 4 independent chains.
template <bool RES, bool DOELU>
__global__ __launch_bounds__(256) void k_msg128v4(const __half* __restrict__ feat,
                                                  const float* __restrict__ el,
                                                  const float* __restrict__ er,
                                                  const int* __restrict__ row_off,
                                                  const int* __restrict__ esrc,
                                                  const float* __restrict__ hres,
                                                  float* __restrict__ out, int nnodes) {
  int t = threadIdx.x;
  int n = blockIdx.x * 16 + (t >> 4);
  if (n >= nnodes) return;
  int lane = t & 15;          // cols lane*8 .. lane*8+7
  int h = lane >> 2;          // this lane's head (32 cols per head)
  int s = row_off[n], e = row_off[n + 1];
  float ern = er[n * 4 + h];
  float4 acc0[4] = {}, acc1[4] = {};
  float den[4] = {0.f, 0.f, 0.f, 0.f};

  for (int c = s; c < e; c += 16) {
    int m = e - c; if (m > 16) m = 16;
    int sjv = 0;
    if (lane < m) sjv = esrc[c + lane];
    // prefetch el: sub-chunks of 4; lane covers edge (lane&3)+4k for head lane>>2
    int e0 = __shfl(sjv, (lane & 3), 16);
    int e1 = __shfl(sjv, (lane & 3) + 4, 16);
    int e2 = __shfl(sjv, (lane & 3) + 8, 16);
    int e3 = __shfl(sjv, (lane & 3) + 12, 16);
    float sel0 = el[e0 * 4 + h];
    float sel1 = el[e1 * 4 + h];
    float sel2 = el[e2 * 4 + h];
    float sel3 = el[e3 * 4 + h];

#define GAT_SUB(KK, SEL)                                                      \
    {                                                                         \
      int b = KK * 4;                                                         \
      if (b < m) {                                                            \
        int mm = m - b; if (mm > 4) mm = 4;                                   \
        _Pragma("unroll")                                                     \
        for (int j = 0; j < 4; ++j) {                                         \
          if (j < mm) {                                                       \
            float ev = __shfl(SEL, (lane & 12) | j, 16);                      \
            float x = ev + ern;                                               \
            x = fmaxf(x, 0.2f * x);                                           \
            float wgt = __expf(x);                                            \
            int sj = __shfl(sjv, b + j, 16);                                  \
            den[j] += wgt;                                                    \
            uint4 raw = *(const uint4*)(feat + (size_t)sj * 128 + lane * 8);  \
            fma8h(acc0[j], acc1[j], wgt, raw);                                \
          }                                                                   \
        }                                                                     \
      }                                                                       \
    }
    GAT_SUB(0, sel0)
    GAT_SUB(1, sel1)
    GAT_SUB(2, sel2)
    GAT_SUB(3, sel3)
#undef GAT_SUB
  }

  float4 A0, A1;
  A0.x = (acc0[0].x + acc0[1].x) + (acc0[2].x + acc0[3].x);
  A0.y = (acc0[0].y + acc0[1].y) + (acc0[2].y + acc0[3].y);
  A0.z = (acc0[0].z + acc0[1].z) + (acc0[2].z + acc0[3].z);
  A0.w = (acc0[0].w + acc0[1].w) + (acc0[2].w + acc0[3].w);
  A1.x = (acc1[0].x + acc1[1].x) + (acc1[2].x + acc1[3].x);
  A1.y = (acc1[0].y + acc1[1].y) + (acc1[2].y + acc1[3].y);
  A1.z = (acc1[0].z + acc1[1].z) + (acc1[2].z + acc1[3].z);
  A1.w = (acc1[0].w + acc1[1].w) + (acc1[2].w + acc1[3].w);
  float D = (den[0] + den[1]) + (den[2] + den[3]);
  float inv = (e > s) ? 1.f / D : 0.f;
  A0.x *= inv; A0.y *= inv; A0.z *= inv; A0.w *= inv;
  A1.x *= inv; A1.y *= inv; A1.z *= inv; A1.w *= inv;
  if (RES) {
    float4 r0 = *(const float4*)(hres + (size_t)n * 128 + lane * 8);
    float4 r1 = *(const float4*)(hres + (size_t)n * 128 + lane * 8 + 4);
    A0.x += r0.x; A0.y += r0.y; A0.z += r0.z; A0.w += r0.w;
    A1.x += r1.x; A1.y += r1.y; A1.z += r1.z; A1.w += r1.w;
  }
  if (DOELU) {
    A0.x = (A0.x > 0.f) ? A0.x : expm1f(A0.x);
    A0.y = (A0.y > 0.f) ? A0.y : expm1f(A0.y);
    A0.z = (A0.z > 0.f) ? A0.z : expm1f(A0.z);
    A0.w = (A0.w > 0.f) ? A0.w : expm1f(A0.w);
    A1.x = (A1.x > 0.f) ? A1.x : expm1f(A1.x);
    A1.y = (A1.y > 0.f) ? A1.y : expm1f(A1.y);
    A1.z = (A1.z > 0.f) ? A1.z : expm1f(A1.z);
    A1.w = (A1.w > 0.f) ? A1.w : expm1f(A1.w);
  }
  *(float4*)(out + (size_t)n * 128 + lane * 8) = A0;
  *(float4*)(out + (size_t)n * 128 + lane * 8 + 4) = A1;
}

// Layer 2: H=1, D=40 fp16; 16 lanes/node, lanes 0..9 carry 4 cols each.
__global__ __launch_bounds__(256) void k_msg40v4(const __half* __restrict__ feat,
                                                 const float* __restrict__ el,
                                                 const float* __restrict__ er,
                                                 const int* __restrict__ row_off,
                                                 const int* __restrict__ esrc,
                                                 const float* __restrict__ res,
                                                 float* __restrict__ out, int nnodes) {
  int t = threadIdx.x;
  int n = blockIdx.x * 16 + (t >> 4);
  if (n >= nnodes) return;
  int lane = t & 15;
  int s = row_off[n], e = row_off[n + 1];
  float ern = er[n];
  float4 acc[2] = {};
  float den[2] = {0.f, 0.f};

  for (int c = s; c < e; c += 16) {
    int m = e - c; if (m > 16) m = 16;
    int sjv = 0;
    if (lane < m) sjv = esrc[c + lane];
    float selv = el[sjv];
    #pragma unroll
    for (int j = 0; j < 16; ++j) {
      if (j < m) {
        float ev = __shfl(selv, j, 16);
        float x = ev + ern;
        x = fmaxf(x, 0.2f * x);
        float wgt = __expf(x);
        int sj = __shfl(sjv, j, 16);
        den[j & 1] += wgt;
        if (lane < 10) {
          uint2 raw = *(const uint2*)(feat + (size_t)sj * 40 + lane * 4);
          const __half2* hp = (const __half2*)&raw;
          float2 f0 = __half22float2(hp[0]);
          float2 f1 = __half22float2(hp[1]);
          acc[j & 1].x += wgt * f0.x;
          acc[j & 1].y += wgt * f0.y;
          acc[j & 1].z += wgt * f1.x;
          acc[j & 1].w += wgt * f1.y;
        }
      }
    }
  }
  float D = den[0] + den[1];
  float inv = (e > s) ? 1.f / D : 0.f;
  if (lane < 10) {
    float4 r = *(const float4*)(res + (size_t)n * 40 + lane * 4);
    float4 A;
    A.x = (acc[0].x + acc[1].x) * inv + r.x;
    A.y = (acc[0].y + acc[1].y) * inv + r.y;
    A.z = (acc[0].z + acc[1].z) * inv + r.z;
    A.w = (acc[0].w + acc[1].w) * inv + r.w;
    *(float4*)(out + (size_t)n * 40 + lane * 4) = A;
  }
}

// ============================= launch =============================
extern "C" void kernel_launch(void* const* d_in, const int* in_sizes, int n_in,
                              void* d_out, int out_size, void* d_ws, size_t ws_size,
                              hipStream_t stream) {
  const float* features = (const float*)d_in[0];
  const float* W0 = (const float*)d_in[1];
  const float* al0 = (const float*)d_in[2];
  const float* ar0 = (const float*)d_in[3];
  const float* W1 = (const float*)d_in[4];
  const float* al1 = (const float*)d_in[5];
  const float* ar1 = (const float*)d_in[6];
  const float* W2 = (const float*)d_in[7];
  const float* al2 = (const float*)d_in[8];
  const float* ar2 = (const float*)d_in[9];
  const float* resW2 = (const float*)d_in[10];
  const int* src = (const int*)d_in[11];
  const int* dst = (const int*)d_in[12];
  float* out = (float*)d_out;

  const int N = NNODES, E = NEDGES;
  char* w = (char*)d_ws;
  auto alloc = [&](size_t bytes) {
    char* p = w;
    w += (bytes + 255) & ~(size_t)255;
    return p;
  };
  int* cnt = (int*)alloc((size_t)N * 4);
  int* row_off = (int*)alloc((size_t)(N + 1) * 4);
  int* bsum = (int*)alloc(256 * 4);
  int* bpre = (int*)alloc(256 * 4);
  int* esrc = (int*)alloc((size_t)E * 4);
  __half* feath = (__half*)alloc((size_t)N * 128 * 2);  // fp16 gather target
  float* res2 = (float*)alloc((size_t)N * 40 * 4);
  float* el = (float*)alloc((size_t)N * 4 * 4);
  float* er = (float*)alloc((size_t)N * 4 * 4);
  float* h1 = (float*)alloc((size_t)N * 128 * 4);
  float* h2 = (float*)alloc((size_t)N * 128 * 4);
  __half* feat2h = feath;  // layer-2 fp16 feat (N x 40) aliases feath

  const int NB = (N + 1023) / 1024;

  // ---- CSR build ----
  hipMemsetAsync(cnt, 0, (size_t)N * 4, stream);
  k_count<<<(E + 255) / 256, 256, 0, stream>>>(dst, cnt, E);
  k_blocksum<<<NB, 1024, 0, stream>>>(cnt, bsum, N);
  k_scanb<<<1, 64, 0, stream>>>(bsum, bpre, NB);
  k_scanwrite<<<NB, 1024, 0, stream>>>(cnt, bpre, row_off, N);
  k_fill<<<(E + 255) / 256, 256, 0, stream>>>(src, dst, cnt, esrc, E);

  const int GB128 = (N + 127) / 128;  // 391
  const int GB64 = (N + 63) / 64;     // 782
  const int GM = (N + 15) / 16;       // 3125

  // ---- layer 0 ----
  k_gemm128<<<GB128, 512, 0, stream>>>(features, W0, al0, ar0, feath, el, er, N);
  k_msg128v4<false, true><<<GM, 256, 0, stream>>>(feath, el, er, row_off, esrc, nullptr, h1, N);

  // ---- layer 1 ----
  k_gemm128<<<GB128, 512, 0, stream>>>(h1, W1, al1, ar1, feath, el, er, N);
  k_msg128v4<true, true><<<GM, 256, 0, stream>>>(feath, el, er, row_off, esrc, h1, h2, N);

  // ---- layer 2 ----
  k_gemm_split<<<GB64, 256, 0, stream>>>(h2, W2, resW2, feat2h, res2, N);
  k_elr40<<<(N + 3) / 4, 256, 0, stream>>>(feat2h, al2, ar2, el, er, N);
  k_msg40v4<<<GM, 256, 0, stream>>>(feat2h, el, er, row_off, esrc, res2, out, N);
}

// Round 5
// 251.961 us; speedup vs baseline: 2.9095x; 1.2946x over previous
//
#include <hip/hip_runtime.h>
#include <hip/hip_fp16.h>

#define NNODES 50000
#define NEDGES 800000

typedef _Float16 f16x8 __attribute__((ext_vector_type(8)));
typedef float f32x4 __attribute__((ext_vector_type(4)));

// ============================= CSR build =============================
__global__ void k_count(const int* __restrict__ dst, int* __restrict__ cnt, int ne) {
  int e = blockIdx.x * 256 + threadIdx.x;
  if (e < ne) atomicAdd(&cnt[dst[e]], 1);
}

__global__ __launch_bounds__(1024) void k_blocksum(const int* __restrict__ cnt,
                                                   int* __restrict__ bsum, int n) {
  __shared__ int sb[1024];
  int t = threadIdx.x, i = blockIdx.x * 1024 + t;
  sb[t] = (i < n) ? cnt[i] : 0;
  __syncthreads();
  for (int m = 512; m; m >>= 1) {
    if (t < m) sb[t] += sb[t + m];
    __syncthreads();
  }
  if (t == 0) bsum[blockIdx.x] = sb[0];
}

__global__ void k_scanb(const int* __restrict__ bsum, int* __restrict__ bpre, int nb) {
  if (threadIdx.x == 0) {
    int s = 0;
    for (int i = 0; i < nb; ++i) { bpre[i] = s; s += bsum[i]; }
  }
}

__global__ __launch_bounds__(1024) void k_scanwrite(int* __restrict__ cnt,
                                                    const int* __restrict__ bpre,
                                                    int* __restrict__ row_off, int n) {
  __shared__ int sb[1024];
  int t = threadIdx.x, i = blockIdx.x * 1024 + t;
  int v = (i < n) ? cnt[i] : 0;
  sb[t] = v;
  __syncthreads();
  for (int off = 1; off < 1024; off <<= 1) {
    int x = (t >= off) ? sb[t - off] : 0;
    __syncthreads();
    sb[t] += x;
    __syncthreads();
  }
  int incl = sb[t] + bpre[blockIdx.x];
  if (i < n) {
    row_off[i + 1] = incl;
    cnt[i] = incl - v;  // exclusive prefix -> scatter cursor
  }
  if (i == 0) row_off[0] = 0;
}

__global__ void k_fill(const int* __restrict__ src, const int* __restrict__ dst,
                       int* __restrict__ cursor, int* __restrict__ esrc, int ne) {
  int e = blockIdx.x * 256 + threadIdx.x;
  if (e < ne) {
    int pos = atomicAdd(&cursor[dst[e]], 1);
    esrc[pos] = src[e];
  }
}

// ============================= weight prep =============================
// Wt0/Wt1: [144][128] fp16 = [W^T (128 rows) | W@al head cols (4) | W@ar (4) | zeros (8)]
// Wt2:     [96][128]  fp16 = [W2^T (40) | resW2^T (40) | W2@al2 | W2@ar2 | zeros (14)]
__global__ __launch_bounds__(128) void k_prep(const float* __restrict__ W0, const float* __restrict__ al0,
                                              const float* __restrict__ ar0,
                                              const float* __restrict__ W1, const float* __restrict__ al1,
                                              const float* __restrict__ ar1,
                                              const float* __restrict__ W2, const float* __restrict__ resW2,
                                              const float* __restrict__ al2, const float* __restrict__ ar2,
                                              _Float16* __restrict__ Wt0, _Float16* __restrict__ Wt1,
                                              _Float16* __restrict__ Wt2) {
  int b = blockIdx.x, k = threadIdx.x;
  if (b < 288) {
    const float* W = (b < 144) ? W0 : W1;
    const float* al = (b < 144) ? al0 : al1;
    const float* ar = (b < 144) ? ar0 : ar1;
    _Float16* Wt = (b < 144) ? Wt0 : Wt1;
    int c = (b < 144) ? b : b - 144;
    float v = 0.f;
    if (c < 128) {
      v = W[k * 128 + c];
    } else if (c < 136) {
      int h = c - 128;
      const float* av = (h < 4) ? al : ar;
      int hh = h & 3;
      float s = 0.f;
      for (int d = 0; d < 32; ++d) s += W[k * 128 + hh * 32 + d] * av[hh * 32 + d];
      v = s;
    }
    Wt[c * 128 + k] = (_Float16)v;
  } else {
    int c = b - 288;
    float v = 0.f;
    if (c < 40) {
      v = W2[k * 40 + c];
    } else if (c < 80) {
      v = resW2[k * 40 + (c - 40)];
    } else if (c == 80) {
      float s = 0.f;
      for (int d = 0; d < 40; ++d) s += W2[k * 40 + d] * al2[d];
      v = s;
    } else if (c == 81) {
      float s = 0.f;
      for (int d = 0; d < 40; ++d) s += W2[k * 40 + d] * ar2[d];
      v = s;
    }
    Wt2[c * 128 + k] = (_Float16)v;
  }
}

// ============================= MFMA GEMM =============================
// A:[nrows,128] f32. Wtg:[NCT*16][128] fp16 (pre-transposed: row = out col).
// 512 thr / 8 waves, 128 rows per block, wave w -> rows w*16..w*16+15.
// !L2E: C fp16 [N,128] = cols 0..127; el/er from tile 8 cols 0..7.
//  L2E: cols<40 -> C fp16 [N,40]; 40..79 -> resOut f32 [N,40]; 80/81 -> el/er.
template <int NCT, bool L2E>
__global__ __launch_bounds__(512) void k_gemm_mfma(const float* __restrict__ A,
                                                   const _Float16* __restrict__ Wtg,
                                                   __half* __restrict__ C,
                                                   float* __restrict__ resOut,
                                                   float* __restrict__ el,
                                                   float* __restrict__ er, int nrows) {
  __shared__ _Float16 Ah[128 * 136];       // +8 pad halves per row
  __shared__ _Float16 Wl[NCT * 16 * 136];
  int t = threadIdx.x;
  int r0 = blockIdx.x * 128;

  // stage Wt (row-major, already transposed in global)
  for (int q = t; q < NCT * 16 * 16; q += 512) {
    int row = q >> 4, k8 = (q & 15) * 8;
    *(f16x8*)(&Wl[row * 136 + k8]) = *(const f16x8*)(Wtg + row * 128 + k8);
  }
  // stage A, f32 -> fp16
  #pragma unroll
  for (int p = 0; p < 8; ++p) {
    int q = p * 512 + t;
    int r = q >> 5, k4 = (q & 31) * 4;
    float4 v = make_float4(0.f, 0.f, 0.f, 0.f);
    if (r0 + r < nrows) v = *(const float4*)(A + (size_t)(r0 + r) * 128 + k4);
    union { _Float16 h[4]; uint2 u; } pk;
    pk.h[0] = (_Float16)v.x; pk.h[1] = (_Float16)v.y;
    pk.h[2] = (_Float16)v.z; pk.h[3] = (_Float16)v.w;
    *(uint2*)(&Ah[r * 136 + k4]) = pk.u;
  }
  __syncthreads();

  int wave = t >> 6, l = t & 63;
  const _Float16* abase = &Ah[(wave * 16 + (l & 15)) * 136 + ((l >> 4) * 8)];
  const _Float16* bbase = &Wl[(l & 15) * 136 + ((l >> 4) * 8)];

  f32x4 acc[NCT] = {};
  #pragma unroll
  for (int ks = 0; ks < 4; ++ks) {
    f16x8 af = *(const f16x8*)(abase + ks * 32);
    #pragma unroll
    for (int nt = 0; nt < NCT; ++nt) {
      f16x8 bf = *(const f16x8*)(bbase + nt * 16 * 136 + ks * 32);
      acc[nt] = __builtin_amdgcn_mfma_f32_16x16x32_f16(af, bf, acc[nt], 0, 0, 0);
    }
  }

  // epilogue: C/D layout col = l&15, row = (l>>4)*4 + reg
  int cc = l & 15;
  int rbase = r0 + wave * 16 + (l >> 4) * 4;
  #pragma unroll
  for (int r = 0; r < 4; ++r) {
    int row = rbase + r;
    if (row >= nrows) continue;
    if (!L2E) {
      #pragma unroll
      for (int nt = 0; nt < 8; ++nt)
        C[(size_t)row * 128 + nt * 16 + cc] = __float2half_rn(acc[nt][r]);
      float v = acc[8][r];
      if (cc < 4) el[row * 4 + cc] = v;
      else if (cc < 8) er[row * 4 + (cc - 4)] = v;
    } else {
      #pragma unroll
      for (int nt = 0; nt < 6; ++nt) {
        int col = nt * 16 + cc;
        float v = acc[nt][r];
        if (col < 40) C[(size_t)row * 40 + col] = __float2half_rn(v);
        else if (col < 80) resOut[(size_t)row * 40 + (col - 40)] = v;
        else if (col == 80) el[row] = v;
        else if (col == 81) er[row] = v;
      }
    }
  }
}

// ============================= helpers =============================
__device__ __forceinline__ void fma8h(float4& a0, float4& a1, float w, const uint4& r) {
  const __half2* hp = (const __half2*)&r;
  float2 f0 = __half22float2(hp[0]);
  float2 f1 = __half22float2(hp[1]);
  float2 f2 = __half22float2(hp[2]);
  float2 f3 = __half22float2(hp[3]);
  a0.x += w * f0.x; a0.y += w * f0.y; a0.z += w * f1.x; a0.w += w * f1.y;
  a1.x += w * f2.x; a1.y += w * f2.y; a1.z += w * f3.x; a1.w += w * f3.y;
}

// ============================= message passing (fp16 gather) =============
template <bool RES, bool DOELU>
__global__ __launch_bounds__(256) void k_msg128v4(const __half* __restrict__ feat,
                                                  const float* __restrict__ el,
                                                  const float* __restrict__ er,
                                                  const int* __restrict__ row_off,
                                                  const int* __restrict__ esrc,
                                                  const float* __restrict__ hres,
                                                  float* __restrict__ out, int nnodes) {
  int t = threadIdx.x;
  int n = blockIdx.x * 16 + (t >> 4);
  if (n >= nnodes) return;
  int lane = t & 15;          // cols lane*8 .. lane*8+7
  int h = lane >> 2;          // this lane's head
  int s = row_off[n], e = row_off[n + 1];
  float ern = er[n * 4 + h];
  float4 acc0[4] = {}, acc1[4] = {};
  float den[4] = {0.f, 0.f, 0.f, 0.f};

  for (int c = s; c < e; c += 16) {
    int m = e - c; if (m > 16) m = 16;
    int sjv = 0;
    if (lane < m) sjv = esrc[c + lane];
    int e0 = __shfl(sjv, (lane & 3), 16);
    int e1 = __shfl(sjv, (lane & 3) + 4, 16);
    int e2 = __shfl(sjv, (lane & 3) + 8, 16);
    int e3 = __shfl(sjv, (lane & 3) + 12, 16);
    float sel0 = el[e0 * 4 + h];
    float sel1 = el[e1 * 4 + h];
    float sel2 = el[e2 * 4 + h];
    float sel3 = el[e3 * 4 + h];

#define GAT_SUB(KK, SEL)                                                      \
    {                                                                         \
      int b = KK * 4;                                                         \
      if (b < m) {                                                            \
        int mm = m - b; if (mm > 4) mm = 4;                                   \
        _Pragma("unroll")                                                     \
        for (int j = 0; j < 4; ++j) {                                         \
          if (j < mm) {                                                       \
            float ev = __shfl(SEL, (lane & 12) | j, 16);                      \
            float x = ev + ern;                                               \
            x = fmaxf(x, 0.2f * x);                                           \
            float wgt = __expf(x);                                            \
            int sj = __shfl(sjv, b + j, 16);                                  \
            den[j] += wgt;                                                    \
            uint4 raw = *(const uint4*)(feat + (size_t)sj * 128 + lane * 8);  \
            fma8h(acc0[j], acc1[j], wgt, raw);                                \
          }                                                                   \
        }                                                                     \
      }                                                                       \
    }
    GAT_SUB(0, sel0)
    GAT_SUB(1, sel1)
    GAT_SUB(2, sel2)
    GAT_SUB(3, sel3)
#undef GAT_SUB
  }

  float4 A0, A1;
  A0.x = (acc0[0].x + acc0[1].x) + (acc0[2].x + acc0[3].x);
  A0.y = (acc0[0].y + acc0[1].y) + (acc0[2].y + acc0[3].y);
  A0.z = (acc0[0].z + acc0[1].z) + (acc0[2].z + acc0[3].z);
  A0.w = (acc0[0].w + acc0[1].w) + (acc0[2].w + acc0[3].w);
  A1.x = (acc1[0].x + acc1[1].x) + (acc1[2].x + acc1[3].x);
  A1.y = (acc1[0].y + acc1[1].y) + (acc1[2].y + acc1[3].y);
  A1.z = (acc1[0].z + acc1[1].z) + (acc1[2].z + acc1[3].z);
  A1.w = (acc1[0].w + acc1[1].w) + (acc1[2].w + acc1[3].w);
  float D = (den[0] + den[1]) + (den[2] + den[3]);
  float inv = (e > s) ? 1.f / D : 0.f;
  A0.x *= inv; A0.y *= inv; A0.z *= inv; A0.w *= inv;
  A1.x *= inv; A1.y *= inv; A1.z *= inv; A1.w *= inv;
  if (RES) {
    float4 r0 = *(const float4*)(hres + (size_t)n * 128 + lane * 8);
    float4 r1 = *(const float4*)(hres + (size_t)n * 128 + lane * 8 + 4);
    A0.x += r0.x; A0.y += r0.y; A0.z += r0.z; A0.w += r0.w;
    A1.x += r1.x; A1.y += r1.y; A1.z += r1.z; A1.w += r1.w;
  }
  if (DOELU) {
    A0.x = (A0.x > 0.f) ? A0.x : expm1f(A0.x);
    A0.y = (A0.y > 0.f) ? A0.y : expm1f(A0.y);
    A0.z = (A0.z > 0.f) ? A0.z : expm1f(A0.z);
    A0.w = (A0.w > 0.f) ? A0.w : expm1f(A0.w);
    A1.x = (A1.x > 0.f) ? A1.x : expm1f(A1.x);
    A1.y = (A1.y > 0.f) ? A1.y : expm1f(A1.y);
    A1.z = (A1.z > 0.f) ? A1.z : expm1f(A1.z);
    A1.w = (A1.w > 0.f) ? A1.w : expm1f(A1.w);
  }
  *(float4*)(out + (size_t)n * 128 + lane * 8) = A0;
  *(float4*)(out + (size_t)n * 128 + lane * 8 + 4) = A1;
}

__global__ __launch_bounds__(256) void k_msg40v4(const __half* __restrict__ feat,
                                                 const float* __restrict__ el,
                                                 const float* __restrict__ er,
                                                 const int* __restrict__ row_off,
                                                 const int* __restrict__ esrc,
                                                 const float* __restrict__ res,
                                                 float* __restrict__ out, int nnodes) {
  int t = threadIdx.x;
  int n = blockIdx.x * 16 + (t >> 4);
  if (n >= nnodes) return;
  int lane = t & 15;
  int s = row_off[n], e = row_off[n + 1];
  float ern = er[n];
  float4 acc[2] = {};
  float den[2] = {0.f, 0.f};

  for (int c = s; c < e; c += 16) {
    int m = e - c; if (m > 16) m = 16;
    int sjv = 0;
    if (lane < m) sjv = esrc[c + lane];
    float selv = el[sjv];
    #pragma unroll
    for (int j = 0; j < 16; ++j) {
      if (j < m) {
        float ev = __shfl(selv, j, 16);
        float x = ev + ern;
        x = fmaxf(x, 0.2f * x);
        float wgt = __expf(x);
        int sj = __shfl(sjv, j, 16);
        den[j & 1] += wgt;
        if (lane < 10) {
          uint2 raw = *(const uint2*)(feat + (size_t)sj * 40 + lane * 4);
          const __half2* hp = (const __half2*)&raw;
          float2 f0 = __half22float2(hp[0]);
          float2 f1 = __half22float2(hp[1]);
          acc[j & 1].x += wgt * f0.x;
          acc[j & 1].y += wgt * f0.y;
          acc[j & 1].z += wgt * f1.x;
          acc[j & 1].w += wgt * f1.y;
        }
      }
    }
  }
  float D = den[0] + den[1];
  float inv = (e > s) ? 1.f / D : 0.f;
  if (lane < 10) {
    float4 r = *(const float4*)(res + (size_t)n * 40 + lane * 4);
    float4 A;
    A.x = (acc[0].x + acc[1].x) * inv + r.x;
    A.y = (acc[0].y + acc[1].y) * inv + r.y;
    A.z = (acc[0].z + acc[1].z) * inv + r.z;
    A.w = (acc[0].w + acc[1].w) * inv + r.w;
    *(float4*)(out + (size_t)n * 40 + lane * 4) = A;
  }
}

// ============================= launch =============================
extern "C" void kernel_launch(void* const* d_in, const int* in_sizes, int n_in,
                              void* d_out, int out_size, void* d_ws, size_t ws_size,
                              hipStream_t stream) {
  const float* features = (const float*)d_in[0];
  const float* W0 = (const float*)d_in[1];
  const float* al0 = (const float*)d_in[2];
  const float* ar0 = (const float*)d_in[3];
  const float* W1 = (const float*)d_in[4];
  const float* al1 = (const float*)d_in[5];
  const float* ar1 = (const float*)d_in[6];
  const float* W2 = (const float*)d_in[7];
  const float* al2 = (const float*)d_in[8];
  const float* ar2 = (const float*)d_in[9];
  const float* resW2 = (const float*)d_in[10];
  const int* src = (const int*)d_in[11];
  const int* dst = (const int*)d_in[12];
  float* out = (float*)d_out;

  const int N = NNODES, E = NEDGES;
  char* w = (char*)d_ws;
  auto alloc = [&](size_t bytes) {
    char* p = w;
    w += (bytes + 255) & ~(size_t)255;
    return p;
  };
  int* cnt = (int*)alloc((size_t)N * 4);
  int* row_off = (int*)alloc((size_t)(N + 1) * 4);
  int* bsum = (int*)alloc(256 * 4);
  int* bpre = (int*)alloc(256 * 4);
  int* esrc = (int*)alloc((size_t)E * 4);
  __half* feath = (__half*)alloc((size_t)N * 128 * 2);   // fp16 gather target
  float* res2 = (float*)alloc((size_t)N * 40 * 4);
  float* el = (float*)alloc((size_t)N * 4 * 4);
  float* er = (float*)alloc((size_t)N * 4 * 4);
  float* h1 = (float*)alloc((size_t)N * 128 * 4);
  float* h2 = (float*)alloc((size_t)N * 128 * 4);
  _Float16* Wt0 = (_Float16*)alloc(144 * 128 * 2);
  _Float16* Wt1 = (_Float16*)alloc(144 * 128 * 2);
  _Float16* Wt2 = (_Float16*)alloc(96 * 128 * 2);
  __half* feat2h = feath;  // layer-2 fp16 feat (N x 40) aliases feath

  const int NB = (N + 1023) / 1024;

  // ---- weight prep (independent of CSR) ----
  k_prep<<<384, 128, 0, stream>>>(W0, al0, ar0, W1, al1, ar1, W2, resW2, al2, ar2,
                                  Wt0, Wt1, Wt2);

  // ---- CSR build ----
  hipMemsetAsync(cnt, 0, (size_t)N * 4, stream);
  k_count<<<(E + 255) / 256, 256, 0, stream>>>(dst, cnt, E);
  k_blocksum<<<NB, 1024, 0, stream>>>(cnt, bsum, N);
  k_scanb<<<1, 64, 0, stream>>>(bsum, bpre, NB);
  k_scanwrite<<<NB, 1024, 0, stream>>>(cnt, bpre, row_off, N);
  k_fill<<<(E + 255) / 256, 256, 0, stream>>>(src, dst, cnt, esrc, E);

  const int GB128 = (N + 127) / 128;  // 391
  const int GM = (N + 15) / 16;       // 3125

  // ---- layer 0 ----
  k_gemm_mfma<9, false><<<GB128, 512, 0, stream>>>(features, Wt0, feath, nullptr, el, er, N);
  k_msg128v4<false, true><<<GM, 256, 0, stream>>>(feath, el, er, row_off, esrc, nullptr, h1, N);

  // ---- layer 1 ----
  k_gemm_mfma<9, false><<<GB128, 512, 0, stream>>>(h1, Wt1, feath, nullptr, el, er, N);
  k_msg128v4<true, true><<<GM, 256, 0, stream>>>(feath, el, er, row_off, esrc, h1, h2, N);

  // ---- layer 2 (fused W2|resW2|el|er MFMA) ----
  k_gemm_mfma<6, true><<<GB128, 512, 0, stream>>>(h2, Wt2, feat2h, res2, el, er, N);
  k_msg40v4<<<GM, 256, 0, stream>>>(feat2h, el, er, row_off, esrc, res2, out, N);
}